// Round 2
// baseline (119.776 us; speedup 1.0000x reference)
//
#include <hip/hip_runtime.h>

#define N_SAMP 1024
#define XD     128
#define HID    256

// ---------------------------------------------------------------------------
// Workspace layout (float indices):
//   [0, 1024)            S       per-i sum of exp(T1[i,j]) over j
//   [1024]               T0sum   sum over i of T1[i,i]  (diagonal, sans b2)
//   [2048, 2048+256K)    xpbT    (x @ W1x + b1)^T   [HID][N]  (k-major)
//   [next 256K)          ypT     (y @ W1y)^T        [HID][N]  (k-major)
// S/T0sum are zeroed by gemm_xy (ws is poisoned 0xAA before every launch).
// ---------------------------------------------------------------------------

// Kernel 1: the two small GEMMs, writing TRANSPOSED outputs. Thread k owns
// hidden unit k for 4 consecutive rows -> in k-major layout those 4 results
// are contiguous: one float4 store per array. Also zeroes S/T0sum.
__global__ __launch_bounds__(256) void gemm_xy(
    const float* __restrict__ x, const float* __restrict__ y,
    const float* __restrict__ W1, const float* __restrict__ b1,
    float* __restrict__ xpbT, float* __restrict__ ypT,
    float* __restrict__ S, float* __restrict__ T0sum)
{
    const int k  = threadIdx.x;        // hidden unit 0..255
    const int r0 = blockIdx.x * 4;     // 4 rows per block

    // Zero accumulators (256 blocks x 4 = 1024 S entries; block 0: T0sum).
    if (threadIdx.x < 4) S[blockIdx.x * 4 + threadIdx.x] = 0.f;
    if (blockIdx.x == 0 && threadIdx.x == 4) T0sum[0] = 0.f;

    float ax0 = 0.f, ax1 = 0.f, ax2 = 0.f, ax3 = 0.f;
    float ay0 = 0.f, ay1 = 0.f, ay2 = 0.f, ay3 = 0.f;

    #pragma unroll 4
    for (int d = 0; d < XD; ++d) {
        const float wx = W1[d * HID + k];            // coalesced over k
        const float wy = W1[(XD + d) * HID + k];
        ax0 = fmaf(x[(r0 + 0) * XD + d], wx, ax0);   // uniform -> s_load
        ax1 = fmaf(x[(r0 + 1) * XD + d], wx, ax1);
        ax2 = fmaf(x[(r0 + 2) * XD + d], wx, ax2);
        ax3 = fmaf(x[(r0 + 3) * XD + d], wx, ax3);
        ay0 = fmaf(y[(r0 + 0) * XD + d], wy, ay0);
        ay1 = fmaf(y[(r0 + 1) * XD + d], wy, ay1);
        ay2 = fmaf(y[(r0 + 2) * XD + d], wy, ay2);
        ay3 = fmaf(y[(r0 + 3) * XD + d], wy, ay3);
    }

    const float bk = b1[k];
    float4 xs = make_float4(ax0 + bk, ax1 + bk, ax2 + bk, ax3 + bk);
    float4 ys = make_float4(ay0, ay1, ay2, ay3);
    *(float4*)&xpbT[k * N_SAMP + r0] = xs;   // 16B-aligned (r0 % 4 == 0)
    *(float4*)&ypT [k * N_SAMP + r0] = ys;
}

// Kernel 2: pairwise relu-dot + exp row-sums.
// Thread tile = 1 i x 4 j -> 4 accs, 12 VALU per k vs 2 loads.
// Grid 16x64 = 1024 blocks = 4 blocks/CU = 4 waves/SIMD (2x the previous
// latency-hiding capacity); explicit 1-iter register prefetch so each
// unroll-4 chunk's loads are in flight before the FMAs need them.
// NOTE: prefetch at k=255 reads "row 256" of each array -> still inside
// the 256 MiB workspace (xpbT row 256 == ypT row 0; ypT row 256 is dead
// ws space). Value is never consumed.
__global__ __launch_bounds__(256) void pair_lse(
    const float* __restrict__ ypT, const float* __restrict__ xpbT,
    const float* __restrict__ W2,
    float* __restrict__ S, float* __restrict__ T0sum)
{
    const int tid = threadIdx.x;
    const int tj  = tid & 15;              // j sub-block 0..15
    const int ti  = tid >> 4;              // i row 0..15
    const int j0  = blockIdx.x * 64 + tj * 4;   // 16 tiles of 64 j
    const int i0  = blockIdx.y * 16 + ti;       // 64 tiles of 16 i

    float a0 = 0.f, a1 = 0.f, a2 = 0.f, a3 = 0.f;

    float4 xc = *(const float4*)&xpbT[j0];      // k = 0
    float  yc = ypT[i0];

    #pragma unroll 4
    for (int k = 0; k < HID; ++k) {
        const float  w  = W2[k];                              // s_load
        const float4 xn = *(const float4*)&xpbT[(k + 1) * N_SAMP + j0];
        const float  yn = ypT[(k + 1) * N_SAMP + i0];
        a0 = fmaf(fmaxf(yc + xc.x, 0.f), w, a0);
        a1 = fmaf(fmaxf(yc + xc.y, 0.f), w, a1);
        a2 = fmaf(fmaxf(yc + xc.z, 0.f), w, a2);
        a3 = fmaf(fmaxf(yc + xc.w, 0.f), w, a3);
        xc = xn; yc = yn;
    }

    // Row sum of exp over this thread's 4 j's, then across the 16 tj lanes
    // (contiguous within a wave), then one atomic per i per block.
    // |acc| ~ O(1): exp without max-shift is safe in f32.
    {
        float e = __expf(a0) + __expf(a1) + __expf(a2) + __expf(a3);
        #pragma unroll
        for (int off = 8; off; off >>= 1) e += __shfl_xor(e, off, 16);
        if (tj == 0) atomicAdd(&S[i0], e);
    }

    // Diagonal (T0): this block touches i==j iff bj == bi>>2.
    if ((int)blockIdx.x == (int)(blockIdx.y >> 2)) {
        const int d = i0 - j0;
        float dv = 0.f;
        if      (d == 0) dv = a0;
        else if (d == 1) dv = a1;
        else if (d == 2) dv = a2;
        else if (d == 3) dv = a3;
        #pragma unroll
        for (int off = 32; off; off >>= 1) dv += __shfl_xor(dv, off, 64);
        if ((tid & 63) == 0) atomicAdd(T0sum, dv);
    }
}

// Kernel 3: lse[i] = log(S[i]); combine means. Single block.
__global__ __launch_bounds__(256) void finalize(
    const float* __restrict__ S, const float* __restrict__ T0sum,
    const float* __restrict__ b2, float* __restrict__ out)
{
    __shared__ float red[4];
    const int tid = threadIdx.x;

    float ls = 0.f;
    for (int i = tid; i < N_SAMP; i += 256) ls += logf(S[i]);
    #pragma unroll
    for (int off = 32; off; off >>= 1) ls += __shfl_xor(ls, off, 64);
    if ((tid & 63) == 0) red[tid >> 6] = ls;
    __syncthreads();

    if (tid == 0) {
        const float lse_sum = red[0] + red[1] + red[2] + red[3];
        const float t0_mean  = T0sum[0] / (float)N_SAMP + b2[0];
        const float lse_mean = lse_sum / (float)N_SAMP + b2[0] - logf((float)N_SAMP);
        out[0] = t0_mean - lse_mean;
    }
}

extern "C" void kernel_launch(void* const* d_in, const int* in_sizes, int n_in,
                              void* d_out, int out_size, void* d_ws, size_t ws_size,
                              hipStream_t stream)
{
    const float* x  = (const float*)d_in[0];
    const float* y  = (const float*)d_in[1];
    const float* W1 = (const float*)d_in[2];
    const float* b1 = (const float*)d_in[3];
    const float* W2 = (const float*)d_in[4];
    const float* b2 = (const float*)d_in[5];

    float* ws   = (float*)d_ws;
    float* S    = ws;                          // 1024 floats
    float* T0s  = ws + 1024;                   // 1 float
    float* xpbT = ws + 2048;                   // [HID][N]
    float* ypT  = ws + 2048 + HID * N_SAMP;    // [HID][N]

    gemm_xy <<<dim3(N_SAMP / 4), dim3(256), 0, stream>>>(x, y, W1, b1,
                                                         xpbT, ypT, S, T0s);
    pair_lse<<<dim3(16, 64),     dim3(256), 0, stream>>>(ypT, xpbT, W2, S, T0s);
    finalize<<<dim3(1),          dim3(256), 0, stream>>>(S, T0s, b2, (float*)d_out);
}